// Round 4
// baseline (414.693 us; speedup 1.0000x reference)
//
#include <hip/hip_runtime.h>
#include <math.h>

#define NA 5
#define HH 76
#define WW 76
#define HWSZ (HH * WW)          // 5776 floats per plane
#define HW4 (HWSZ / 4)          // 1444 vec4 chunks per plane
#define HALF4 (HW4 / 2)         // 722 chunks per half-plane task
#define GRID 1024               // exactly co-resident at 4 blocks/CU x 256 CU
#define NTASK (512 * NA * 2)    // 5120 half-plane tasks = GRID * 5
#define OBJECT_SCALE 5.0f
#define SIL_THRESH 0.6f

// ws layout: [0]: done-counter (zeroed by hipMemsetAsync)
//            [PART_OFF + blk*8 ...): per-block partial sums (5 used, 8 stride)
#define PART_OFF 8192

__constant__ float ANC_W[NA] = {0.57273f, 1.87446f, 3.33843f, 7.88282f, 9.77052f};
__constant__ float ANC_H[NA] = {0.677385f, 2.06253f, 5.47434f, 3.52778f, 9.16828f};

typedef float v4f __attribute__((ext_vector_type(4)));

__device__ __forceinline__ float frcp(float x) { return __builtin_amdgcn_rcpf(x); }
__device__ __forceinline__ float sigm_fast(float x) { return frcp(1.0f + __expf(-x)); }

// 1024 blocks x 5 half-plane tasks each: perfectly balanced, zero grid tail.
// Prep is fused (wave-uniform recompute). IoU only where it can exceed
// SIL_THRESH (area-ratio window on pw+ph). Final reduction fused via
// last-block-done (device-scope atomic on ws[0]).
__global__ __launch_bounds__(256, 4) void
region_loss_main(const float* __restrict__ pred, const float* __restrict__ target,
                 float* __restrict__ ws, float* __restrict__ out) {
    float ax = 0.f, ay = 0.f, aw_ = 0.f, ah_ = 0.f, ac = 0.f;

    for (int it = 0; it < 5; ++it) {
        const int t    = blockIdx.x + (it << 10);   // task 0..5119
        const int ba   = t >> 1;                    // plane (b*NA + a)
        const int half = t & 1;
        const int b    = ba / NA;
        const int a    = ba - b * NA;

        // ---- fused prep (identical math to original prep_kernel; uniform) ----
        const float gx = target[b * 4 + 0] * (float)WW;
        const float gy = target[b * 4 + 1] * (float)HH;
        const float gw = target[b * 4 + 2] * (float)WW;
        const float gh = target[b * 4 + 3] * (float)HH;
        int best = 0;
        {
            float bestv = -1.0f;
#pragma unroll
            for (int aa = 0; aa < NA; ++aa) {
                float aw = ANC_W[aa], ah = ANC_H[aa];
                float inter = fminf(gw, aw) * fminf(gh, ah);
                float uni = gw * gh + aw * ah - inter;
                float iou = inter / uni;
                if (iou > bestv) { bestv = iou; best = aa; }  // first-max wins ties
            }
        }
        const int gi = (int)gx;
        const int gj = (int)gy;
        const float tx_s = gx - (float)gi;
        const float ty_s = gy - (float)gj;
        const float tw_s = logf(gw / ANC_W[best]);
        const float th_s = logf(gh / ANC_H[best]);

        const float anw = ANC_W[a], anh = ANC_H[a];
        const bool anchit = (a == best);
        const float gxm = gx - gw * 0.5f, gxM = gx + gw * 0.5f;
        const float gym = gy - gh * 0.5f, gyM = gy + gh * 0.5f;
        const float garea = gw * gh;
        // area-ratio window for possible iou > 0.6 (widened for fp safety)
        const float c_lo = logf(0.6f * garea / (anw * anh)) - 1e-3f;
        const float c_hi = c_lo + 1.0216512f + 2e-3f;   // log(1/0.36) + slack

        const float* base = pred + (size_t)ba * 5 * HWSZ;

        auto compute = [&](int r, v4f px, v4f py, v4f pw, v4f ph, v4f pc) {
            const int e0 = r * 4;
            const int j  = r / 19;            // 19 chunks per row
            const int i0 = e0 - j * WW;
            const bool rowhit = anchit && (j == gj) && (gi >= i0) && (gi < i0 + 4);
#pragma unroll
            for (int k = 0; k < 4; ++k) {
                float sx = sigm_fast(px[k]);
                float sy = sigm_fast(py[k]);
                float sc = sigm_fast(pc[k]);
                const bool special = rowhit && ((i0 + k) == gi);

                float cmask = 1.0f, tconf = 0.0f;
                const float tt = pw[k] + ph[k];
                if (((tt > c_lo) & (tt < c_hi)) | special) {
                    float bw = __expf(pw[k]) * anw;
                    float bh = __expf(ph[k]) * anh;
                    float bx = sx + (float)(i0 + k);
                    float by = sy + (float)j;
                    float mx = fminf(gxm, bx - bw * 0.5f);
                    float Mx = fmaxf(gxM, bx + bw * 0.5f);
                    float my = fminf(gym, by - bh * 0.5f);
                    float My = fmaxf(gyM, by + bh * 0.5f);
                    float cw = gw + bw - (Mx - mx);
                    float ch = gh + bh - (My - my);
                    float carea = (cw <= 0.f || ch <= 0.f) ? 0.f : cw * ch;
                    float uarea = garea + bw * bh - carea;
                    float iou = carea * frcp(uarea);
                    cmask = (iou > SIL_THRESH) ? 0.f : 1.f;
                    if (special) { cmask = OBJECT_SCALE; tconf = iou; }
                }

                float tx = special ? tx_s : 0.5f;
                float ty = special ? ty_s : 0.5f;
                float tw = special ? tw_s : 0.0f;
                float th = special ? th_s : 0.0f;
                float dx = sx - tx, dy = sy - ty;
                float dw = pw[k] - tw, dh = ph[k] - th;
                float dc = sc - tconf;
                ax += dx * dx;
                ay += dy * dy;
                aw_ += dw * dw;
                ah_ += dh * dh;
                ac += cmask * dc * dc;
            }
        };

        const int rbeg = half * HALF4;
        const int rend = rbeg + HALF4;
        int r = rbeg + threadIdx.x;
        // unrolled x2: two chunks per stream, 10 loads in flight
        for (; r + 256 < rend; r += 512) {
            const int r2 = r + 256;
            v4f px0 = __builtin_nontemporal_load((const v4f*)(base + r * 4));
            v4f py0 = __builtin_nontemporal_load((const v4f*)(base + HWSZ + r * 4));
            v4f pw0 = __builtin_nontemporal_load((const v4f*)(base + 2 * HWSZ + r * 4));
            v4f ph0 = __builtin_nontemporal_load((const v4f*)(base + 3 * HWSZ + r * 4));
            v4f pc0 = __builtin_nontemporal_load((const v4f*)(base + 4 * HWSZ + r * 4));
            v4f px1 = __builtin_nontemporal_load((const v4f*)(base + r2 * 4));
            v4f py1 = __builtin_nontemporal_load((const v4f*)(base + HWSZ + r2 * 4));
            v4f pw1 = __builtin_nontemporal_load((const v4f*)(base + 2 * HWSZ + r2 * 4));
            v4f ph1 = __builtin_nontemporal_load((const v4f*)(base + 3 * HWSZ + r2 * 4));
            v4f pc1 = __builtin_nontemporal_load((const v4f*)(base + 4 * HWSZ + r2 * 4));
            compute(r, px0, py0, pw0, ph0, pc0);
            compute(r2, px1, py1, pw1, ph1, pc1);
        }
        for (; r < rend; r += 256) {
            v4f px = __builtin_nontemporal_load((const v4f*)(base + r * 4));
            v4f py = __builtin_nontemporal_load((const v4f*)(base + HWSZ + r * 4));
            v4f pw = __builtin_nontemporal_load((const v4f*)(base + 2 * HWSZ + r * 4));
            v4f ph = __builtin_nontemporal_load((const v4f*)(base + 3 * HWSZ + r * 4));
            v4f pc = __builtin_nontemporal_load((const v4f*)(base + 4 * HWSZ + r * 4));
            compute(r, px, py, pw, ph, pc);
        }
    }

    // ---- block reduction: wave shuffle -> LDS -> per-block partials ----
    __shared__ float sred[4][5];
    __shared__ int lastflag;
    const int lane = threadIdx.x & 63;
    const int wid  = threadIdx.x >> 6;
    float vals[5] = {ax, ay, aw_, ah_, ac};
#pragma unroll
    for (int v = 0; v < 5; ++v) {
        float x = vals[v];
#pragma unroll
        for (int off = 32; off > 0; off >>= 1) x += __shfl_down(x, off, 64);
        if (lane == 0) sred[wid][v] = x;
    }
    __syncthreads();
    if (threadIdx.x < 5) {
        float s = sred[0][threadIdx.x] + sred[1][threadIdx.x] +
                  sred[2][threadIdx.x] + sred[3][threadIdx.x];
        ws[PART_OFF + blockIdx.x * 8 + threadIdx.x] = s;
    }
    __syncthreads();   // all partial stores issued (each wave drains vmem at barrier)

    // ---- last-block-done: fused final reduction ----
    if (threadIdx.x == 0) {
        unsigned prev = __hip_atomic_fetch_add((unsigned*)ws, 1u,
                                               __ATOMIC_ACQ_REL,
                                               __HIP_MEMORY_SCOPE_AGENT);
        lastflag = (prev == GRID - 1);
    }
    __syncthreads();
    if (!lastflag) return;

    __threadfence();   // acquire: invalidate stale cached partials
    float s0 = 0.f, s1 = 0.f, s2 = 0.f, s3 = 0.f, s4 = 0.f;
    for (int i = threadIdx.x; i < GRID; i += 256) {
        const float* p = ws + PART_OFF + i * 8;
        s0 += p[0]; s1 += p[1]; s2 += p[2]; s3 += p[3]; s4 += p[4];
    }
    float fvals[5] = {s0, s1, s2, s3, s4};
#pragma unroll
    for (int v = 0; v < 5; ++v) {
        float x = fvals[v];
#pragma unroll
        for (int off = 32; off > 0; off >>= 1) x += __shfl_down(x, off, 64);
        if (lane == 0) sred[wid][v] = x;
    }
    __syncthreads();
    if (threadIdx.x == 0) {
        float lx = (sred[0][0] + sred[1][0] + sred[2][0] + sred[3][0]) * 0.5f;
        float ly = (sred[0][1] + sred[1][1] + sred[2][1] + sred[3][1]) * 0.5f;
        float lw = (sred[0][2] + sred[1][2] + sred[2][2] + sred[3][2]) * 0.5f;
        float lh = (sred[0][3] + sred[1][3] + sred[2][3] + sred[3][3]) * 0.5f;
        float lc = (sred[0][4] + sred[1][4] + sred[2][4] + sred[3][4]) * 0.5f;
        out[0] = lx + ly + lw + lh + lc;
        out[1] = lx;
        out[2] = ly;
        out[3] = lw;
        out[4] = lh;
        out[5] = lc;
    }
}

extern "C" void kernel_launch(void* const* d_in, const int* in_sizes, int n_in,
                              void* d_out, int out_size, void* d_ws, size_t ws_size,
                              hipStream_t stream) {
    const float* pred   = (const float*)d_in[0];
    const float* target = (const float*)d_in[1];
    float* ws  = (float*)d_ws;
    float* out = (float*)d_out;

    hipMemsetAsync(d_ws, 0, 4, stream);   // zero the done-counter
    region_loss_main<<<GRID, 256, 0, stream>>>(pred, target, ws, out);
}

// Round 5
// 372.105 us; speedup vs baseline: 1.1145x; 1.1145x over previous
//
#include <hip/hip_runtime.h>
#include <math.h>

#define NA 5
#define HH 76
#define WW 76
#define HWSZ (HH * WW)          // 5776
#define HW4 (HWSZ / 4)          // 1444 vec4 chunks per plane
#define NBLK (512 * NA)         // 2560 main-kernel blocks
#define OBJECT_SCALE 5.0f
#define SIL_THRESH 0.6f

// ws layout (floats): [PART_OFF + blk*8 ...): per-block partial sums (5 used, 8 stride)
#define PART_OFF 8192

__constant__ float ANC_W[NA] = {0.57273f, 1.87446f, 3.33843f, 7.88282f, 9.77052f};
__constant__ float ANC_H[NA] = {0.677385f, 2.06253f, 5.47434f, 3.52778f, 9.16828f};

typedef float v4f __attribute__((ext_vector_type(4)));

__device__ __forceinline__ float frcp(float x) { return __builtin_amdgcn_rcpf(x); }
__device__ __forceinline__ float sigm_fast(float x) { return frcp(1.0f + __expf(-x)); }

// One block per (b, a) plane. Prep is fused (wave-uniform recompute from target).
// IoU is only computed where it can possibly exceed SIL_THRESH:
//   iou <= min(garea,barea)/max(garea,barea), so iou > 0.6 requires
//   pw+ph in (log(0.6*garea/(anw*anh)), that + log(1/0.36)).  execz-skips the
//   expensive path for the vast majority of waves.
// Stream loop unrolled x2: 10 vec4 loads in flight per wave-iteration.
__global__ __launch_bounds__(256, 4) void
region_loss_main(const float* __restrict__ pred, const float* __restrict__ target,
                 float* __restrict__ ws) {
    const int ba = blockIdx.x;
    const int b  = ba / NA;
    const int a  = ba - b * NA;

    // ---- fused prep (identical math to the old prep_kernel; wave-uniform) ----
    const float gx = target[b * 4 + 0] * (float)WW;
    const float gy = target[b * 4 + 1] * (float)HH;
    const float gw = target[b * 4 + 2] * (float)WW;
    const float gh = target[b * 4 + 3] * (float)HH;
    int best = 0;
    {
        float bestv = -1.0f;
#pragma unroll
        for (int aa = 0; aa < NA; ++aa) {
            float aw = ANC_W[aa], ah = ANC_H[aa];
            float inter = fminf(gw, aw) * fminf(gh, ah);
            float uni = gw * gh + aw * ah - inter;
            float iou = inter / uni;
            if (iou > bestv) { bestv = iou; best = aa; }  // first-max wins ties
        }
    }
    const int gi = (int)gx;
    const int gj = (int)gy;
    const float tx_s = gx - (float)gi;
    const float ty_s = gy - (float)gj;
    const float tw_s = logf(gw / ANC_W[best]);
    const float th_s = logf(gh / ANC_H[best]);

    const float anw = ANC_W[a], anh = ANC_H[a];
    const bool anchit = (a == best);
    const float gxm = gx - gw * 0.5f, gxM = gx + gw * 0.5f;
    const float gym = gy - gh * 0.5f, gyM = gy + gh * 0.5f;
    const float garea = gw * gh;
    // area-ratio window for possible iou > 0.6 (widened for fp safety)
    const float c_lo = logf(0.6f * garea / (anw * anh)) - 1e-3f;
    const float c_hi = c_lo + 1.0216512f + 2e-3f;     // log(1/0.36) + slack

    const float* base = pred + (size_t)ba * 5 * HWSZ;
    float ax = 0.f, ay = 0.f, aw_ = 0.f, ah_ = 0.f, ac = 0.f;

    auto compute = [&](int r, v4f px, v4f py, v4f pw, v4f ph, v4f pc) {
        const int e0 = r * 4;
        const int j  = r / 19;            // 19 chunks per row
        const int i0 = e0 - j * WW;
        const bool rowhit = anchit && (j == gj) && (gi >= i0) && (gi < i0 + 4);
#pragma unroll
        for (int k = 0; k < 4; ++k) {
            float sx = sigm_fast(px[k]);
            float sy = sigm_fast(py[k]);
            float sc = sigm_fast(pc[k]);
            const bool special = rowhit && ((i0 + k) == gi);

            float cmask = 1.0f, tconf = 0.0f;
            const float t = pw[k] + ph[k];
            if (((t > c_lo) & (t < c_hi)) | special) {
                float bw = __expf(pw[k]) * anw;
                float bh = __expf(ph[k]) * anh;
                float bx = sx + (float)(i0 + k);
                float by = sy + (float)j;
                float mx = fminf(gxm, bx - bw * 0.5f);
                float Mx = fmaxf(gxM, bx + bw * 0.5f);
                float my = fminf(gym, by - bh * 0.5f);
                float My = fmaxf(gyM, by + bh * 0.5f);
                float cw = gw + bw - (Mx - mx);
                float ch = gh + bh - (My - my);
                float carea = (cw <= 0.f || ch <= 0.f) ? 0.f : cw * ch;
                float uarea = garea + bw * bh - carea;
                float iou = carea * frcp(uarea);
                cmask = (iou > SIL_THRESH) ? 0.f : 1.f;
                if (special) { cmask = OBJECT_SCALE; tconf = iou; }
            }

            float tx = special ? tx_s : 0.5f;
            float ty = special ? ty_s : 0.5f;
            float tw = special ? tw_s : 0.0f;
            float th = special ? th_s : 0.0f;
            float dx = sx - tx, dy = sy - ty;
            float dw = pw[k] - tw, dh = ph[k] - th;
            float dc = sc - tconf;
            ax += dx * dx;
            ay += dy * dy;
            aw_ += dw * dw;
            ah_ += dh * dh;
            ac += cmask * dc * dc;
        }
    };

    int r = threadIdx.x;
    // unrolled x2: two chunks per stream, 10 loads issued before compute
    for (; r + 256 < HW4; r += 512) {
        const int r2 = r + 256;
        v4f px0 = __builtin_nontemporal_load((const v4f*)(base + r * 4));
        v4f py0 = __builtin_nontemporal_load((const v4f*)(base + HWSZ + r * 4));
        v4f pw0 = __builtin_nontemporal_load((const v4f*)(base + 2 * HWSZ + r * 4));
        v4f ph0 = __builtin_nontemporal_load((const v4f*)(base + 3 * HWSZ + r * 4));
        v4f pc0 = __builtin_nontemporal_load((const v4f*)(base + 4 * HWSZ + r * 4));
        v4f px1 = __builtin_nontemporal_load((const v4f*)(base + r2 * 4));
        v4f py1 = __builtin_nontemporal_load((const v4f*)(base + HWSZ + r2 * 4));
        v4f pw1 = __builtin_nontemporal_load((const v4f*)(base + 2 * HWSZ + r2 * 4));
        v4f ph1 = __builtin_nontemporal_load((const v4f*)(base + 3 * HWSZ + r2 * 4));
        v4f pc1 = __builtin_nontemporal_load((const v4f*)(base + 4 * HWSZ + r2 * 4));
        compute(r, px0, py0, pw0, ph0, pc0);
        compute(r2, px1, py1, pw1, ph1, pc1);
    }
    for (; r < HW4; r += 256) {
        v4f px = __builtin_nontemporal_load((const v4f*)(base + r * 4));
        v4f py = __builtin_nontemporal_load((const v4f*)(base + HWSZ + r * 4));
        v4f pw = __builtin_nontemporal_load((const v4f*)(base + 2 * HWSZ + r * 4));
        v4f ph = __builtin_nontemporal_load((const v4f*)(base + 3 * HWSZ + r * 4));
        v4f pc = __builtin_nontemporal_load((const v4f*)(base + 4 * HWSZ + r * 4));
        compute(r, px, py, pw, ph, pc);
    }

    // block reduction: wave shuffle -> LDS -> per-block partial store (NO atomics)
    __shared__ float sred[4][5];
    int lane = threadIdx.x & 63;
    int wid  = threadIdx.x >> 6;
    float vals[5] = {ax, ay, aw_, ah_, ac};
#pragma unroll
    for (int v = 0; v < 5; ++v) {
        float x = vals[v];
#pragma unroll
        for (int off = 32; off > 0; off >>= 1) x += __shfl_down(x, off, 64);
        if (lane == 0) sred[wid][v] = x;
    }
    __syncthreads();
    if (threadIdx.x < 5) {
        float s = sred[0][threadIdx.x] + sred[1][threadIdx.x] +
                  sred[2][threadIdx.x] + sred[3][threadIdx.x];
        ws[PART_OFF + blockIdx.x * 8 + threadIdx.x] = s;
    }
}

// Reduce 2560 x 5 partials and write the 6 outputs.
__global__ __launch_bounds__(256) void
reduce_finish(const float* __restrict__ ws, float* __restrict__ out) {
    float s0 = 0.f, s1 = 0.f, s2 = 0.f, s3 = 0.f, s4 = 0.f;
    for (int i = threadIdx.x; i < NBLK; i += 256) {
        const float* p = ws + PART_OFF + i * 8;
        s0 += p[0]; s1 += p[1]; s2 += p[2]; s3 += p[3]; s4 += p[4];
    }
    __shared__ float sred[4][5];
    int lane = threadIdx.x & 63;
    int wid  = threadIdx.x >> 6;
    float vals[5] = {s0, s1, s2, s3, s4};
#pragma unroll
    for (int v = 0; v < 5; ++v) {
        float x = vals[v];
#pragma unroll
        for (int off = 32; off > 0; off >>= 1) x += __shfl_down(x, off, 64);
        if (lane == 0) sred[wid][v] = x;
    }
    __syncthreads();
    if (threadIdx.x == 0) {
        float lx = (sred[0][0] + sred[1][0] + sred[2][0] + sred[3][0]) * 0.5f;
        float ly = (sred[0][1] + sred[1][1] + sred[2][1] + sred[3][1]) * 0.5f;
        float lw = (sred[0][2] + sred[1][2] + sred[2][2] + sred[3][2]) * 0.5f;
        float lh = (sred[0][3] + sred[1][3] + sred[2][3] + sred[3][3]) * 0.5f;
        float lc = (sred[0][4] + sred[1][4] + sred[2][4] + sred[3][4]) * 0.5f;
        out[0] = lx + ly + lw + lh + lc;
        out[1] = lx;
        out[2] = ly;
        out[3] = lw;
        out[4] = lh;
        out[5] = lc;
    }
}

extern "C" void kernel_launch(void* const* d_in, const int* in_sizes, int n_in,
                              void* d_out, int out_size, void* d_ws, size_t ws_size,
                              hipStream_t stream) {
    const float* pred   = (const float*)d_in[0];
    const float* target = (const float*)d_in[1];
    float* ws  = (float*)d_ws;
    float* out = (float*)d_out;
    int bs = in_sizes[1] / 4;   // 512

    region_loss_main<<<bs * NA, 256, 0, stream>>>(pred, target, ws);
    reduce_finish<<<1, 256, 0, stream>>>(ws, out);
}